// Round 6
// baseline (210.014 us; speedup 1.0000x reference)
//
#include <hip/hip_runtime.h>
#include <stdint.h>

typedef __attribute__((ext_vector_type(8))) short bf16x8;
typedef __attribute__((ext_vector_type(4))) float f32x4;

__device__ __forceinline__ uint16_t f2bf(float f) {
  union { float f; uint32_t u; } a; a.f = f;
  uint32_t u = a.u;
  u += 0x7FFFu + ((u >> 16) & 1u);   // RTNE
  return (uint16_t)(u >> 16);
}

// packed f32x2 -> bf16x2, RTNE (epilogue quality)
__device__ __forceinline__ uint32_t pk_bf16(float a, float b) {
#if __has_builtin(__builtin_amdgcn_cvt_pk_bf16_f32)
  auto r = __builtin_amdgcn_cvt_pk_bf16_f32(a, b);
  uint32_t u; __builtin_memcpy(&u, &r, sizeof(u));
  return u;
#else
  return (uint32_t)f2bf(a) | ((uint32_t)f2bf(b) << 16);
#endif
}

// packed f32x2 -> bf16x2, fast path (truncation fallback via v_perm) — P matrix only
__device__ __forceinline__ uint32_t pk_bf16_fast(float a, float b) {
#if __has_builtin(__builtin_amdgcn_cvt_pk_bf16_f32)
  auto r = __builtin_amdgcn_cvt_pk_bf16_f32(a, b);
  uint32_t u; __builtin_memcpy(&u, &r, sizeof(u));
  return u;
#else
  uint32_t ua, ub;
  __builtin_memcpy(&ua, &a, 4); __builtin_memcpy(&ub, &b, 4);
  return __builtin_amdgcn_perm(ub, ua, 0x07060302u);  // {b.hi16, a.hi16}
#endif
}

__device__ __forceinline__ float fast_exp2(float x) {
#if __has_builtin(__builtin_amdgcn_exp2f)
  return __builtin_amdgcn_exp2f(x);   // raw v_exp_f32
#else
  return exp2f(x);
#endif
}

__device__ __forceinline__ void gld_lds16(const uint16_t* g, uint16_t* l) {
  __builtin_amdgcn_global_load_lds(
      (const __attribute__((address_space(1))) void*)g,
      (__attribute__((address_space(3))) void*)l, 16, 0, 0);
}

// ---------------- fused cast fp32 -> bf16 ----------------
__global__ void cast_all(const float* __restrict__ x, const float* __restrict__ wq,
                         const float* __restrict__ wk, const float* __restrict__ wv,
                         const float* __restrict__ wff,
                         uint16_t* __restrict__ xb, uint16_t* __restrict__ wqb,
                         uint16_t* __restrict__ wkb, uint16_t* __restrict__ wvb,
                         uint16_t* __restrict__ wffb) {
  int i = blockIdx.x * blockDim.x + threadIdx.x;  // float4 group index
  const float* src; uint16_t* dst; int off;
  if (i < 1048576)      { src = x;   dst = xb;   off = i; }
  else if (i < 1310720) { src = wq;  dst = wqb;  off = i - 1048576; }
  else if (i < 1572864) { src = wk;  dst = wkb;  off = i - 1310720; }
  else if (i < 1835008) { src = wv;  dst = wvb;  off = i - 1572864; }
  else                  { src = wff; dst = wffb; off = i - 1835008; }
  float4 v = ((const float4*)src)[off];
  uint2 o; o.x = pk_bf16(v.x, v.y); o.y = pk_bf16(v.z, v.w);
  ((uint2*)dst)[off] = o;
}

// ---------------- shared GEMM mainloop: acc[i][j] = A[i,:] dot B[j,:], K=1024 ----------------
// i = wm*64+mt*16+quad*4+r  (A-row), j = wn*64+nt*16+lrow (B-row)
__device__ __forceinline__ void gemm_tile(const uint16_t* __restrict__ Abase,
                                          const uint16_t* __restrict__ Bbase,
                                          uint16_t* lds, f32x4 acc[4][4]) {
  const int tid  = threadIdx.x;
  const int w    = tid >> 6;
  const int lane = tid & 63;
  const int wm   = w >> 1, wn = w & 1;
  const int lrow = lane & 15;
  const int quad = lane >> 4;
  const int srow = lane >> 3;
  const int lc   = (lane & 7) ^ srow;
  const int sx   = lrow & 7;
  uint16_t* a_lds = lds;
  uint16_t* b_lds = lds + 8192;

#pragma unroll
  for (int mt = 0; mt < 4; ++mt)
#pragma unroll
    for (int nt = 0; nt < 4; ++nt)
      acc[mt][nt] = (f32x4){0.f, 0.f, 0.f, 0.f};

  const uint16_t* ag = Abase + (size_t)(w * 32 + srow) * 1024 + lc * 8;
  const uint16_t* bg = Bbase + (size_t)(w * 32 + srow) * 1024 + lc * 8;

  for (int k0 = 0; k0 < 1024; k0 += 64) {
#pragma unroll
    for (int i8 = 0; i8 < 4; ++i8) {
      gld_lds16(ag + (size_t)i8 * 8 * 1024 + k0, a_lds + (w * 4 + i8) * 512);
      gld_lds16(bg + (size_t)i8 * 8 * 1024 + k0, b_lds + (w * 4 + i8) * 512);
    }
    __syncthreads();
#pragma unroll
    for (int ks = 0; ks < 2; ++ks) {
      bf16x8 af[4], bfr[4];
      const int c = ((ks * 4 + quad) ^ sx) << 3;
#pragma unroll
      for (int mt = 0; mt < 4; ++mt)
        af[mt] = *(const bf16x8*)(a_lds + (wm * 64 + mt * 16 + lrow) * 64 + c);
#pragma unroll
      for (int nt = 0; nt < 4; ++nt)
        bfr[nt] = *(const bf16x8*)(b_lds + (wn * 64 + nt * 16 + lrow) * 64 + c);
#pragma unroll
      for (int mt = 0; mt < 4; ++mt)
#pragma unroll
        for (int nt = 0; nt < 4; ++nt)
          acc[mt][nt] = __builtin_amdgcn_mfma_f32_16x16x32_bf16(af[mt], bfr[nt], acc[mt][nt], 0, 0, 0);
    }
    __syncthreads();
  }
}

// ---------------- QKV projection, LDS-transposed coalesced epilogue ----------------
__global__ __launch_bounds__(256) void gemm_qkv(
    const uint16_t* __restrict__ x,
    const uint16_t* __restrict__ wq, const uint16_t* __restrict__ wk, const uint16_t* __restrict__ wv,
    uint16_t* __restrict__ qo, uint16_t* __restrict__ ko, uint16_t* __restrict__ vto) {
  __shared__ __align__(16) uint16_t lds[17408];   // 34816 B; mainloop uses first 32 KB
  const int m0 = blockIdx.x * 128, n0 = blockIdx.y * 128, z = blockIdx.z;
  f32x4 acc[4][4];
  if (z < 2) {
    const uint16_t* W = (z == 0) ? wq : wk;
    gemm_tile(W + (size_t)n0 * 1024, x + (size_t)m0 * 1024, lds, acc);
  } else {
    gemm_tile(x + (size_t)m0 * 1024, wv + (size_t)n0 * 1024, lds, acc);
  }

  const int tid = threadIdx.x;
  const int lane = tid & 63, w = tid >> 6;
  const int wm = w >> 1, wn = w & 1, lrow = lane & 15, quad = lane >> 4;
  const float scale = (z == 0) ? 0.045084222f : 1.0f;  // fold log2(e)/sqrt(1024) into Q

#pragma unroll
  for (int mt = 0; mt < 4; ++mt)
#pragma unroll
    for (int nt = 0; nt < 4; ++nt) {
      int i0 = wm * 64 + mt * 16 + quad * 4;
      int j  = wn * 64 + nt * 16 + lrow;
      uint2 dd;
      dd.x = pk_bf16(acc[mt][nt][0] * scale, acc[mt][nt][1] * scale);
      dd.y = pk_bf16(acc[mt][nt][2] * scale, acc[mt][nt][3] * scale);
      *(uint2*)(&lds[j * 136 + i0]) = dd;
    }
  __syncthreads();

  uint16_t* outp = (z == 0) ? qo : (z == 1) ? ko : vto;
  if (z < 2) {
#pragma unroll
    for (int it = 0; it < 8; ++it) {
      int idx = it * 256 + tid;
      int jj = idx >> 4, cc = idx & 15;                 // token jj, feature-chunk cc
      uint4 v = *(const uint4*)(&lds[jj * 136 + cc * 8]);
      int m = m0 + jj, n = n0 + cc * 8;
      int b = m >> 11, s = m & 2047, h = n >> 6, dh = n & 63;
      *(uint4*)(outp + ((size_t)((b * 16 + h) * 2048 + s)) * 64 + dh) = v;
    }
  } else {
    int b = m0 >> 11, sbase = m0 & 2047;
#pragma unroll
    for (int it = 0; it < 8; ++it) {
      int idx = it * 256 + tid;
      int ff = idx >> 4, cc = idx & 15;                 // feature ff, token-chunk cc
      uint4 v = *(const uint4*)(&lds[ff * 136 + cc * 8]);
      int n = n0 + ff, h = n >> 6, dh = n & 63;
      *(uint4*)(outp + ((size_t)((b * 16 + h) * 64 + dh)) * 2048 + sbase + cc * 8) = v;
    }
  }
}

// ---------------- FF: out = ao @ Wff^T + bff, LDS-transposed fp32 epilogue ----------------
__global__ __launch_bounds__(256) void gemm_ff(
    const uint16_t* __restrict__ ao, const uint16_t* __restrict__ wff,
    const float* __restrict__ bff, float* __restrict__ out) {
  __shared__ __align__(16) uint16_t lds[17408];   // 34816 B = 128*68 floats exactly
  const int m0 = blockIdx.x * 128, n0 = blockIdx.y * 128;
  f32x4 acc[4][4];
  gemm_tile(wff + (size_t)n0 * 1024, ao + (size_t)m0 * 1024, lds, acc);

  const int tid = threadIdx.x;
  const int lane = tid & 63, w = tid >> 6;
  const int wm = w >> 1, wn = w & 1, lrow = lane & 15, quad = lane >> 4;
  float* fl = (float*)lds;

#pragma unroll
  for (int p = 0; p < 2; ++p) {   // feature half
    if (wm == p) {
#pragma unroll
      for (int mt = 0; mt < 4; ++mt)
#pragma unroll
        for (int nt = 0; nt < 4; ++nt) {
          int i0 = mt * 16 + quad * 4;            // feature within half
          int j  = wn * 64 + nt * 16 + lrow;      // token
          *(f32x4*)(&fl[j * 68 + i0]) = acc[mt][nt];
        }
    }
    __syncthreads();
#pragma unroll
    for (int it = 0; it < 8; ++it) {
      int idx = it * 256 + tid;
      int jj = idx >> 4, cc = idx & 15;           // token jj, feature-chunk cc (4 floats)
      f32x4 v = *(const f32x4*)(&fl[jj * 68 + cc * 4]);
      int n = n0 + p * 64 + cc * 4;
      f32x4 bias = *(const f32x4*)(bff + n);
      f32x4 vv = v + bias;
      *(f32x4*)(out + (size_t)(m0 + jj) * 1024 + n) = vv;
    }
    __syncthreads();
  }
}

// ---------------- flash attention, transposed domain, 64 q-rows per wave ----------------
// 2 waves/block (128 qrows). K/V fragments read once per iter, reused across
// 4 Q-chunks -> per-CU LDS traffic drops 1.5x vs 32q/wave.
__global__ __launch_bounds__(128, 2) void attn(
    const uint16_t* __restrict__ q, const uint16_t* __restrict__ k,
    const uint16_t* __restrict__ vt, uint16_t* __restrict__ ao) {
  __shared__ __align__(16) uint16_t k_lds[2][4096];   // [buf][key 64][dh 64], swizzled
  __shared__ __align__(16) uint16_t v_lds[2][4096];   // [buf][dh 64][key 64], swizzled
  __shared__ __align__(16) uint16_t p_lds[2][4096];   // per-wave [qrow 64][key 64], swizzled
  const int tid = threadIdx.x, w = tid >> 6, lane = tid & 63;
  const int lrow = lane & 15, quad = lane >> 4;
  const int srow = lane >> 3, lc = (lane & 7) ^ srow, sx = lrow & 7;
  const int bh = blockIdx.y, qb = blockIdx.x;
  const uint16_t* Q = q  + (size_t)bh * (2048 * 64);
  const uint16_t* K = k  + (size_t)bh * (2048 * 64);
  const uint16_t* V = vt + (size_t)bh * (64 * 2048);
  uint16_t* pw = p_lds[w];
  const int cswz = (lrow & 7) << 1;

  const int qr0 = qb * 128 + w * 64;
  bf16x8 qf[4][2];   // [qchunk][ks]: B-fragment, n=qrow, k=dh  (scale pre-folded)
#pragma unroll
  for (int qh = 0; qh < 4; ++qh)
#pragma unroll
    for (int ks = 0; ks < 2; ++ks)
      qf[qh][ks] = *(const bf16x8*)(Q + (size_t)(qr0 + qh * 16 + lrow) * 64 + ks * 32 + quad * 8);

  f32x4 o[4][4];     // O^T accum: [qchunk][dt], dh = dt*16+quad*4+r, qrow = lrow
#pragma unroll
  for (int qh = 0; qh < 4; ++qh)
#pragma unroll
    for (int dt = 0; dt < 4; ++dt) o[qh][dt] = (f32x4){0.f, 0.f, 0.f, 0.f};
  float ls[4] = {0.f, 0.f, 0.f, 0.f};

  auto stage = [&](int kb, int bi) {
#pragma unroll
    for (int i4 = 0; i4 < 4; ++i4) {
      int i8 = w * 4 + i4;
      gld_lds16(K + (size_t)(kb * 64 + i8 * 8 + srow) * 64 + lc * 8, &k_lds[bi][i8 * 512]);
      gld_lds16(V + (size_t)(i8 * 8 + srow) * 2048 + kb * 64 + lc * 8, &v_lds[bi][i8 * 512]);
    }
  };
  stage(0, 0);

  for (int kb = 0; kb < 32; ++kb) {
    const int bi = kb & 1;
    __syncthreads();
    if (kb + 1 < 32) stage(kb + 1, bi ^ 1);

    // S^T[key][qrow]: s[qh][kt], key = kt*16+quad*4+r, qrow = qh*16+lrow
    f32x4 s[4][4];
#pragma unroll
    for (int qh = 0; qh < 4; ++qh)
#pragma unroll
      for (int kt = 0; kt < 4; ++kt) s[qh][kt] = (f32x4){0.f, 0.f, 0.f, 0.f};
#pragma unroll
    for (int ks = 0; ks < 2; ++ks) {
      const int c = ((ks * 4 + quad) ^ sx) << 3;
#pragma unroll
      for (int kt = 0; kt < 4; ++kt) {
        bf16x8 kf = *(const bf16x8*)(&k_lds[bi][(kt * 16 + lrow) * 64 + c]);
#pragma unroll
        for (int qh = 0; qh < 4; ++qh)
          s[qh][kt] = __builtin_amdgcn_mfma_f32_16x16x32_bf16(kf, qf[qh][ks], s[qh][kt], 0, 0, 0);
      }
    }

    // exp2 (scale pre-folded, no max), accumulate l, pack+write P^T
#pragma unroll
    for (int qh = 0; qh < 4; ++qh)
#pragma unroll
      for (int kt = 0; kt < 4; ++kt) {
        float p0 = fast_exp2(s[qh][kt][0]);
        float p1 = fast_exp2(s[qh][kt][1]);
        float p2 = fast_exp2(s[qh][kt][2]);
        float p3 = fast_exp2(s[qh][kt][3]);
        ls[qh] += (p0 + p1) + (p2 + p3);
        uint2 dd; dd.x = pk_bf16_fast(p0, p1); dd.y = pk_bf16_fast(p2, p3);
        *(uint2*)(pw + (qh * 16 + lrow) * 64 + (((kt * 4 + quad) ^ cswz) << 2)) = dd;
      }

    // O^T += V^T * P^T  (same-wave LDS, no barrier)
#pragma unroll
    for (int ks = 0; ks < 2; ++ks) {
      bf16x8 pa[4];
#pragma unroll
      for (int qh = 0; qh < 4; ++qh)
        pa[qh] = *(const bf16x8*)(pw + (qh * 16 + lrow) * 64 + (((ks * 8 + quad * 2) ^ cswz) << 2));
      const int c = ((ks * 4 + quad) ^ sx) << 3;
#pragma unroll
      for (int dt = 0; dt < 4; ++dt) {
        bf16x8 vf = *(const bf16x8*)(&v_lds[bi][(dt * 16 + lrow) * 64 + c]);
#pragma unroll
        for (int qh = 0; qh < 4; ++qh)
          o[qh][dt] = __builtin_amdgcn_mfma_f32_16x16x32_bf16(vf, pa[qh], o[qh][dt], 0, 0, 0);
      }
    }
  }

  const int b = bh >> 4, h = bh & 15;
#pragma unroll
  for (int qh = 0; qh < 4; ++qh) {
    float l = ls[qh];
    l += __shfl_xor(l, 16);
    l += __shfl_xor(l, 32);
    float inv = 1.0f / l;
    int sg = qr0 + qh * 16 + lrow;
#pragma unroll
    for (int dt = 0; dt < 4; ++dt) {
      uint2 dd;
      dd.x = pk_bf16(o[qh][dt][0] * inv, o[qh][dt][1] * inv);
      dd.y = pk_bf16(o[qh][dt][2] * inv, o[qh][dt][3] * inv);
      *(uint2*)(ao + (size_t)(b * 2048 + sg) * 1024 + h * 64 + dt * 16 + quad * 4) = dd;
    }
  }
}

extern "C" void kernel_launch(void* const* d_in, const int* in_sizes, int n_in,
                              void* d_out, int out_size, void* d_ws, size_t ws_size,
                              hipStream_t stream) {
  const float* x   = (const float*)d_in[0];
  const float* Wq  = (const float*)d_in[1];
  const float* Wk  = (const float*)d_in[2];
  const float* Wv  = (const float*)d_in[3];
  const float* Wff = (const float*)d_in[4];
  const float* bff = (const float*)d_in[5];
  float* out = (float*)d_out;

  uint16_t* ws = (uint16_t*)d_ws;
  uint16_t* x_bf   = ws;                 // 4M elems
  uint16_t* wq_bf  = ws + 4194304;       // 1M
  uint16_t* wk_bf  = ws + 5242880;       // 1M
  uint16_t* wv_bf  = ws + 6291456;       // 1M
  uint16_t* wff_bf = ws + 7340032;       // 1M
  uint16_t* q_bf   = ws + 8388608;       // 4M  (b,h,s,dh), pre-scaled by log2e/sqrt(D)
  uint16_t* k_bf   = ws + 12582912;      // 4M  (b,h,s,dh)
  uint16_t* vt_bf  = ws + 16777216;      // 4M  (b,h,dh,s)
  uint16_t* ao_bf  = ws + 20971520;      // 4M  (b,s,h*64+dh)

  cast_all<<<8192, 256, 0, stream>>>(x, Wq, Wk, Wv, Wff, x_bf, wq_bf, wk_bf, wv_bf, wff_bf);

  gemm_qkv<<<dim3(32, 8, 3), 256, 0, stream>>>(x_bf, wq_bf, wk_bf, wv_bf, q_bf, k_bf, vt_bf);
  attn<<<dim3(16, 32), 128, 0, stream>>>(q_bf, k_bf, vt_bf, ao_bf);
  gemm_ff<<<dim3(32, 8), 256, 0, stream>>>(ao_bf, wff_bf, bff, out);
}

// Round 7
// 203.175 us; speedup vs baseline: 1.0337x; 1.0337x over previous
//
#include <hip/hip_runtime.h>
#include <stdint.h>

typedef __attribute__((ext_vector_type(8))) short bf16x8;
typedef __attribute__((ext_vector_type(4))) float f32x4;

__device__ __forceinline__ uint16_t f2bf(float f) {
  union { float f; uint32_t u; } a; a.f = f;
  uint32_t u = a.u;
  u += 0x7FFFu + ((u >> 16) & 1u);   // RTNE
  return (uint16_t)(u >> 16);
}

// packed f32x2 -> bf16x2, RTNE (epilogue quality)
__device__ __forceinline__ uint32_t pk_bf16(float a, float b) {
#if __has_builtin(__builtin_amdgcn_cvt_pk_bf16_f32)
  auto r = __builtin_amdgcn_cvt_pk_bf16_f32(a, b);
  uint32_t u; __builtin_memcpy(&u, &r, sizeof(u));
  return u;
#else
  return (uint32_t)f2bf(a) | ((uint32_t)f2bf(b) << 16);
#endif
}

// packed f32x2 -> bf16x2, fast path (truncation fallback via v_perm) — P matrix only
__device__ __forceinline__ uint32_t pk_bf16_fast(float a, float b) {
#if __has_builtin(__builtin_amdgcn_cvt_pk_bf16_f32)
  auto r = __builtin_amdgcn_cvt_pk_bf16_f32(a, b);
  uint32_t u; __builtin_memcpy(&u, &r, sizeof(u));
  return u;
#else
  uint32_t ua, ub;
  __builtin_memcpy(&ua, &a, 4); __builtin_memcpy(&ub, &b, 4);
  return __builtin_amdgcn_perm(ub, ua, 0x07060302u);  // {b.hi16, a.hi16}
#endif
}

__device__ __forceinline__ float fast_exp2(float x) {
#if __has_builtin(__builtin_amdgcn_exp2f)
  return __builtin_amdgcn_exp2f(x);   // raw v_exp_f32
#else
  return exp2f(x);
#endif
}

__device__ __forceinline__ void gld_lds16(const uint16_t* g, uint16_t* l) {
  __builtin_amdgcn_global_load_lds(
      (const __attribute__((address_space(1))) void*)g,
      (__attribute__((address_space(3))) void*)l, 16, 0, 0);
}

// ---------------- fused cast fp32 -> bf16 ----------------
__global__ void cast_all(const float* __restrict__ x, const float* __restrict__ wq,
                         const float* __restrict__ wk, const float* __restrict__ wv,
                         const float* __restrict__ wff,
                         uint16_t* __restrict__ xb, uint16_t* __restrict__ wqb,
                         uint16_t* __restrict__ wkb, uint16_t* __restrict__ wvb,
                         uint16_t* __restrict__ wffb) {
  int i = blockIdx.x * blockDim.x + threadIdx.x;  // float4 group index
  const float* src; uint16_t* dst; int off;
  if (i < 1048576)      { src = x;   dst = xb;   off = i; }
  else if (i < 1310720) { src = wq;  dst = wqb;  off = i - 1048576; }
  else if (i < 1572864) { src = wk;  dst = wkb;  off = i - 1310720; }
  else if (i < 1835008) { src = wv;  dst = wvb;  off = i - 1572864; }
  else                  { src = wff; dst = wffb; off = i - 1835008; }
  float4 v = ((const float4*)src)[off];
  uint2 o; o.x = pk_bf16(v.x, v.y); o.y = pk_bf16(v.z, v.w);
  ((uint2*)dst)[off] = o;
}

// ---------------- shared GEMM mainloop: acc[i][j] = A[i,:] dot B[j,:], K=1024 ----------------
__device__ __forceinline__ void gemm_tile(const uint16_t* __restrict__ Abase,
                                          const uint16_t* __restrict__ Bbase,
                                          uint16_t* lds, f32x4 acc[4][4]) {
  const int tid  = threadIdx.x;
  const int w    = tid >> 6;
  const int lane = tid & 63;
  const int wm   = w >> 1, wn = w & 1;
  const int lrow = lane & 15;
  const int quad = lane >> 4;
  const int srow = lane >> 3;
  const int lc   = (lane & 7) ^ srow;
  const int sx   = lrow & 7;
  uint16_t* a_lds = lds;
  uint16_t* b_lds = lds + 8192;

#pragma unroll
  for (int mt = 0; mt < 4; ++mt)
#pragma unroll
    for (int nt = 0; nt < 4; ++nt)
      acc[mt][nt] = (f32x4){0.f, 0.f, 0.f, 0.f};

  const uint16_t* ag = Abase + (size_t)(w * 32 + srow) * 1024 + lc * 8;
  const uint16_t* bg = Bbase + (size_t)(w * 32 + srow) * 1024 + lc * 8;

  for (int k0 = 0; k0 < 1024; k0 += 64) {
#pragma unroll
    for (int i8 = 0; i8 < 4; ++i8) {
      gld_lds16(ag + (size_t)i8 * 8 * 1024 + k0, a_lds + (w * 4 + i8) * 512);
      gld_lds16(bg + (size_t)i8 * 8 * 1024 + k0, b_lds + (w * 4 + i8) * 512);
    }
    __syncthreads();
#pragma unroll
    for (int ks = 0; ks < 2; ++ks) {
      bf16x8 af[4], bfr[4];
      const int c = ((ks * 4 + quad) ^ sx) << 3;
#pragma unroll
      for (int mt = 0; mt < 4; ++mt)
        af[mt] = *(const bf16x8*)(a_lds + (wm * 64 + mt * 16 + lrow) * 64 + c);
#pragma unroll
      for (int nt = 0; nt < 4; ++nt)
        bfr[nt] = *(const bf16x8*)(b_lds + (wn * 64 + nt * 16 + lrow) * 64 + c);
#pragma unroll
      for (int mt = 0; mt < 4; ++mt)
#pragma unroll
        for (int nt = 0; nt < 4; ++nt)
          acc[mt][nt] = __builtin_amdgcn_mfma_f32_16x16x32_bf16(af[mt], bfr[nt], acc[mt][nt], 0, 0, 0);
    }
    __syncthreads();
  }
}

// ---------------- fused Q+K projection: share the x tile, 2x MFMA per barrier ----------------
// acc[z][i][j]: i = W-row (feature, wm*64+mt*16+quad*4+r), j = x-row (token, wn*64+nt*16+lrow)
__global__ __launch_bounds__(256, 2) void gemm_qk(
    const uint16_t* __restrict__ x,
    const uint16_t* __restrict__ wq, const uint16_t* __restrict__ wk,
    uint16_t* __restrict__ qo, uint16_t* __restrict__ ko) {
  __shared__ __align__(16) uint16_t lds[24576];   // 48 KB: x | Wq | Wk tiles
  const int m0 = blockIdx.x * 128, n0 = blockIdx.y * 128;
  const int tid = threadIdx.x, w = tid >> 6, lane = tid & 63;
  const int wm = w >> 1, wn = w & 1, lrow = lane & 15, quad = lane >> 4;
  const int srow = lane >> 3, lc = (lane & 7) ^ srow, sx = lrow & 7;
  uint16_t* x_lds = lds;            // B operand
  uint16_t* wq_lds = lds + 8192;    // A operand (Q)
  uint16_t* wk_lds = lds + 16384;   // A operand (K)

  f32x4 acc[2][4][4];
#pragma unroll
  for (int z = 0; z < 2; ++z)
#pragma unroll
    for (int mt = 0; mt < 4; ++mt)
#pragma unroll
      for (int nt = 0; nt < 4; ++nt)
        acc[z][mt][nt] = (f32x4){0.f, 0.f, 0.f, 0.f};

  const uint16_t* xg = x  + (size_t)(m0 + w * 32 + srow) * 1024 + lc * 8;
  const uint16_t* qg = wq + (size_t)(n0 + w * 32 + srow) * 1024 + lc * 8;
  const uint16_t* kg = wk + (size_t)(n0 + w * 32 + srow) * 1024 + lc * 8;

  for (int k0 = 0; k0 < 1024; k0 += 64) {
#pragma unroll
    for (int i8 = 0; i8 < 4; ++i8) {
      gld_lds16(xg + (size_t)i8 * 8 * 1024 + k0, x_lds  + (w * 4 + i8) * 512);
      gld_lds16(qg + (size_t)i8 * 8 * 1024 + k0, wq_lds + (w * 4 + i8) * 512);
      gld_lds16(kg + (size_t)i8 * 8 * 1024 + k0, wk_lds + (w * 4 + i8) * 512);
    }
    __syncthreads();
#pragma unroll
    for (int ks = 0; ks < 2; ++ks) {
      const int c = ((ks * 4 + quad) ^ sx) << 3;
      bf16x8 xb[4], wa[4];
#pragma unroll
      for (int nt = 0; nt < 4; ++nt)
        xb[nt] = *(const bf16x8*)(x_lds + (wn * 64 + nt * 16 + lrow) * 64 + c);
#pragma unroll
      for (int mt = 0; mt < 4; ++mt)
        wa[mt] = *(const bf16x8*)(wq_lds + (wm * 64 + mt * 16 + lrow) * 64 + c);
#pragma unroll
      for (int mt = 0; mt < 4; ++mt)
#pragma unroll
        for (int nt = 0; nt < 4; ++nt)
          acc[0][mt][nt] = __builtin_amdgcn_mfma_f32_16x16x32_bf16(wa[mt], xb[nt], acc[0][mt][nt], 0, 0, 0);
#pragma unroll
      for (int mt = 0; mt < 4; ++mt)
        wa[mt] = *(const bf16x8*)(wk_lds + (wm * 64 + mt * 16 + lrow) * 64 + c);
#pragma unroll
      for (int mt = 0; mt < 4; ++mt)
#pragma unroll
        for (int nt = 0; nt < 4; ++nt)
          acc[1][mt][nt] = __builtin_amdgcn_mfma_f32_16x16x32_bf16(wa[mt], xb[nt], acc[1][mt][nt], 0, 0, 0);
    }
    __syncthreads();
  }

  // epilogue per z: LDS-transpose [token j][feature i0, stride 136] then 16B stores
#pragma unroll
  for (int z = 0; z < 2; ++z) {
    const float scale = (z == 0) ? 0.045084222f : 1.0f;  // fold log2(e)/sqrt(1024) into Q
#pragma unroll
    for (int mt = 0; mt < 4; ++mt)
#pragma unroll
      for (int nt = 0; nt < 4; ++nt) {
        int i0 = wm * 64 + mt * 16 + quad * 4;
        int j  = wn * 64 + nt * 16 + lrow;
        uint2 dd;
        dd.x = pk_bf16(acc[z][mt][nt][0] * scale, acc[z][mt][nt][1] * scale);
        dd.y = pk_bf16(acc[z][mt][nt][2] * scale, acc[z][mt][nt][3] * scale);
        *(uint2*)(&lds[j * 136 + i0]) = dd;
      }
    __syncthreads();
    uint16_t* outp = (z == 0) ? qo : ko;
#pragma unroll
    for (int it = 0; it < 8; ++it) {
      int idx = it * 256 + tid;
      int jj = idx >> 4, cc = idx & 15;                 // token jj, feature-chunk cc
      uint4 v = *(const uint4*)(&lds[jj * 136 + cc * 8]);
      int m = m0 + jj, n = n0 + cc * 8;
      int b = m >> 11, s = m & 2047, h = n >> 6, dh = n & 63;
      *(uint4*)(outp + ((size_t)((b * 16 + h) * 2048 + s)) * 64 + dh) = v;
    }
    __syncthreads();
  }
}

// ---------------- V projection: A=x, B=Wv -> (b,h,dh,s), LDS-transposed epilogue ----------------
__global__ __launch_bounds__(256) void gemm_v(
    const uint16_t* __restrict__ x, const uint16_t* __restrict__ wv,
    uint16_t* __restrict__ vto) {
  __shared__ __align__(16) uint16_t lds[17408];
  const int m0 = blockIdx.x * 128, n0 = blockIdx.y * 128;
  f32x4 acc[4][4];
  gemm_tile(x + (size_t)m0 * 1024, wv + (size_t)n0 * 1024, lds, acc);

  const int tid = threadIdx.x;
  const int lane = tid & 63, w = tid >> 6;
  const int wm = w >> 1, wn = w & 1, lrow = lane & 15, quad = lane >> 4;

#pragma unroll
  for (int mt = 0; mt < 4; ++mt)
#pragma unroll
    for (int nt = 0; nt < 4; ++nt) {
      int i0 = wm * 64 + mt * 16 + quad * 4;   // token (4 consecutive s)
      int j  = wn * 64 + nt * 16 + lrow;       // feature
      uint2 dd;
      dd.x = pk_bf16(acc[mt][nt][0], acc[mt][nt][1]);
      dd.y = pk_bf16(acc[mt][nt][2], acc[mt][nt][3]);
      *(uint2*)(&lds[j * 136 + i0]) = dd;
    }
  __syncthreads();

  int b = m0 >> 11, sbase = m0 & 2047;
#pragma unroll
  for (int it = 0; it < 8; ++it) {
    int idx = it * 256 + tid;
    int ff = idx >> 4, cc = idx & 15;                 // feature ff, token-chunk cc
    uint4 v = *(const uint4*)(&lds[ff * 136 + cc * 8]);
    int n = n0 + ff, h = n >> 6, dh = n & 63;
    *(uint4*)(vto + ((size_t)((b * 16 + h) * 64 + dh)) * 2048 + sbase + cc * 8) = v;
  }
}

// ---------------- FF: out = ao @ Wff^T + bff, LDS-transposed fp32 epilogue ----------------
__global__ __launch_bounds__(256) void gemm_ff(
    const uint16_t* __restrict__ ao, const uint16_t* __restrict__ wff,
    const float* __restrict__ bff, float* __restrict__ out) {
  __shared__ __align__(16) uint16_t lds[17408];   // 34816 B = 128*68 floats exactly
  const int m0 = blockIdx.x * 128, n0 = blockIdx.y * 128;
  f32x4 acc[4][4];
  gemm_tile(wff + (size_t)n0 * 1024, ao + (size_t)m0 * 1024, lds, acc);

  const int tid = threadIdx.x;
  const int lane = tid & 63, w = tid >> 6;
  const int wm = w >> 1, wn = w & 1, lrow = lane & 15, quad = lane >> 4;
  float* fl = (float*)lds;

#pragma unroll
  for (int p = 0; p < 2; ++p) {   // feature half
    if (wm == p) {
#pragma unroll
      for (int mt = 0; mt < 4; ++mt)
#pragma unroll
        for (int nt = 0; nt < 4; ++nt) {
          int i0 = mt * 16 + quad * 4;            // feature within half
          int j  = wn * 64 + nt * 16 + lrow;      // token
          *(f32x4*)(&fl[j * 68 + i0]) = acc[mt][nt];
        }
    }
    __syncthreads();
#pragma unroll
    for (int it = 0; it < 8; ++it) {
      int idx = it * 256 + tid;
      int jj = idx >> 4, cc = idx & 15;           // token jj, feature-chunk cc (4 floats)
      f32x4 v = *(const f32x4*)(&fl[jj * 68 + cc * 4]);
      int n = n0 + p * 64 + cc * 4;
      f32x4 bias = *(const f32x4*)(bff + n);
      f32x4 vv = v + bias;
      *(f32x4*)(out + (size_t)(m0 + jj) * 1024 + n) = vv;
    }
    __syncthreads();
  }
}

// ---------------- flash attention (R5 version): 32 q-rows per wave, 256 thr ----------------
__global__ __launch_bounds__(256, 2) void attn(
    const uint16_t* __restrict__ q, const uint16_t* __restrict__ k,
    const uint16_t* __restrict__ vt, uint16_t* __restrict__ ao) {
  __shared__ __align__(16) uint16_t k_lds[2][4096];   // [buf][key 64][dh 64], swizzled
  __shared__ __align__(16) uint16_t v_lds[2][4096];   // [buf][dh 64][key 64], swizzled
  __shared__ __align__(16) uint16_t p_lds[4][2048];   // per-wave [qrow 32][key 64], swizzled
  const int tid = threadIdx.x, w = tid >> 6, lane = tid & 63;
  const int lrow = lane & 15, quad = lane >> 4;
  const int srow = lane >> 3, lc = (lane & 7) ^ srow, sx = lrow & 7;
  const int bh = blockIdx.y, qb = blockIdx.x;
  const uint16_t* Q = q  + (size_t)bh * (2048 * 64);
  const uint16_t* K = k  + (size_t)bh * (2048 * 64);
  const uint16_t* V = vt + (size_t)bh * (64 * 2048);
  uint16_t* pw = p_lds[w];
  const int cswz = (lrow & 7) << 1;

  const int qr0 = qb * 128 + w * 32;
  bf16x8 qf[2][2];   // [qhalf][ks]: B-fragment, n=qrow, k=dh  (scale pre-folded)
#pragma unroll
  for (int qh = 0; qh < 2; ++qh)
#pragma unroll
    for (int ks = 0; ks < 2; ++ks)
      qf[qh][ks] = *(const bf16x8*)(Q + (size_t)(qr0 + qh * 16 + lrow) * 64 + ks * 32 + quad * 8);

  f32x4 o[2][4];     // O^T accum: [qhalf][dt], dh = dt*16+quad*4+r, qrow = lrow
#pragma unroll
  for (int qh = 0; qh < 2; ++qh)
#pragma unroll
    for (int dt = 0; dt < 4; ++dt) o[qh][dt] = (f32x4){0.f, 0.f, 0.f, 0.f};
  float ls[2] = {0.f, 0.f};

  auto stage = [&](int kb, int bi) {
#pragma unroll
    for (int i2 = 0; i2 < 2; ++i2) {
      int i8 = w * 2 + i2;
      gld_lds16(K + (size_t)(kb * 64 + i8 * 8 + srow) * 64 + lc * 8, &k_lds[bi][i8 * 512]);
      gld_lds16(V + (size_t)(i8 * 8 + srow) * 2048 + kb * 64 + lc * 8, &v_lds[bi][i8 * 512]);
    }
  };
  stage(0, 0);

  for (int kb = 0; kb < 32; ++kb) {
    const int bi = kb & 1;
    __syncthreads();
    if (kb + 1 < 32) stage(kb + 1, bi ^ 1);

    // S^T[key][qrow]: s[qh][kt], key = kt*16+quad*4+r, qrow = qh*16+lrow
    f32x4 s[2][4];
#pragma unroll
    for (int qh = 0; qh < 2; ++qh)
#pragma unroll
      for (int kt = 0; kt < 4; ++kt) s[qh][kt] = (f32x4){0.f, 0.f, 0.f, 0.f};
#pragma unroll
    for (int ks = 0; ks < 2; ++ks) {
      const int c = ((ks * 4 + quad) ^ sx) << 3;
#pragma unroll
      for (int kt = 0; kt < 4; ++kt) {
        bf16x8 kf = *(const bf16x8*)(&k_lds[bi][(kt * 16 + lrow) * 64 + c]);
        s[0][kt] = __builtin_amdgcn_mfma_f32_16x16x32_bf16(kf, qf[0][ks], s[0][kt], 0, 0, 0);
        s[1][kt] = __builtin_amdgcn_mfma_f32_16x16x32_bf16(kf, qf[1][ks], s[1][kt], 0, 0, 0);
      }
    }

    // exp2 (scale pre-folded, no max), accumulate l, pack+write P^T
#pragma unroll
    for (int qh = 0; qh < 2; ++qh)
#pragma unroll
      for (int kt = 0; kt < 4; ++kt) {
        float p0 = fast_exp2(s[qh][kt][0]);
        float p1 = fast_exp2(s[qh][kt][1]);
        float p2 = fast_exp2(s[qh][kt][2]);
        float p3 = fast_exp2(s[qh][kt][3]);
        ls[qh] += (p0 + p1) + (p2 + p3);
        uint2 dd; dd.x = pk_bf16_fast(p0, p1); dd.y = pk_bf16_fast(p2, p3);
        *(uint2*)(pw + (qh * 16 + lrow) * 64 + (((kt * 4 + quad) ^ cswz) << 2)) = dd;
      }

    // O^T += V^T * P^T  (same-wave LDS, no barrier)
#pragma unroll
    for (int ks = 0; ks < 2; ++ks) {
      bf16x8 pa0 = *(const bf16x8*)(pw + lrow * 64 + (((ks * 8 + quad * 2) ^ cswz) << 2));
      bf16x8 pa1 = *(const bf16x8*)(pw + (16 + lrow) * 64 + (((ks * 8 + quad * 2) ^ cswz) << 2));
      const int c = ((ks * 4 + quad) ^ sx) << 3;
#pragma unroll
      for (int dt = 0; dt < 4; ++dt) {
        bf16x8 vf = *(const bf16x8*)(&v_lds[bi][(dt * 16 + lrow) * 64 + c]);
        o[0][dt] = __builtin_amdgcn_mfma_f32_16x16x32_bf16(vf, pa0, o[0][dt], 0, 0, 0);
        o[1][dt] = __builtin_amdgcn_mfma_f32_16x16x32_bf16(vf, pa1, o[1][dt], 0, 0, 0);
      }
    }
  }

  const int b = bh >> 4, h = bh & 15;
#pragma unroll
  for (int qh = 0; qh < 2; ++qh) {
    float l = ls[qh];
    l += __shfl_xor(l, 16);
    l += __shfl_xor(l, 32);
    float inv = 1.0f / l;
    int sg = qr0 + qh * 16 + lrow;
#pragma unroll
    for (int dt = 0; dt < 4; ++dt) {
      uint2 dd;
      dd.x = pk_bf16(o[qh][dt][0] * inv, o[qh][dt][1] * inv);
      dd.y = pk_bf16(o[qh][dt][2] * inv, o[qh][dt][3] * inv);
      *(uint2*)(ao + (size_t)(b * 2048 + sg) * 1024 + h * 64 + dt * 16 + quad * 4) = dd;
    }
  }
}

extern "C" void kernel_launch(void* const* d_in, const int* in_sizes, int n_in,
                              void* d_out, int out_size, void* d_ws, size_t ws_size,
                              hipStream_t stream) {
  const float* x   = (const float*)d_in[0];
  const float* Wq  = (const float*)d_in[1];
  const float* Wk  = (const float*)d_in[2];
  const float* Wv  = (const float*)d_in[3];
  const float* Wff = (const float*)d_in[4];
  const float* bff = (const float*)d_in[5];
  float* out = (float*)d_out;

  uint16_t* ws = (uint16_t*)d_ws;
  uint16_t* x_bf   = ws;                 // 4M elems
  uint16_t* wq_bf  = ws + 4194304;       // 1M
  uint16_t* wk_bf  = ws + 5242880;       // 1M
  uint16_t* wv_bf  = ws + 6291456;       // 1M
  uint16_t* wff_bf = ws + 7340032;       // 1M
  uint16_t* q_bf   = ws + 8388608;       // 4M  (b,h,s,dh), pre-scaled by log2e/sqrt(D)
  uint16_t* k_bf   = ws + 12582912;      // 4M  (b,h,s,dh)
  uint16_t* vt_bf  = ws + 16777216;      // 4M  (b,h,dh,s)
  uint16_t* ao_bf  = ws + 20971520;      // 4M  (b,s,h*64+dh)

  cast_all<<<8192, 256, 0, stream>>>(x, Wq, Wk, Wv, Wff, x_bf, wq_bf, wk_bf, wv_bf, wff_bf);

  gemm_qk<<<dim3(32, 8), 256, 0, stream>>>(x_bf, wq_bf, wk_bf, q_bf, k_bf);
  gemm_v<<<dim3(32, 8), 256, 0, stream>>>(x_bf, wv_bf, vt_bf);
  attn<<<dim3(16, 32), 256, 0, stream>>>(q_bf, k_bf, vt_bf, ao_bf);
  gemm_ff<<<dim3(32, 8), 256, 0, stream>>>(ao_bf, wff_bf, bff, out);
}

// Round 9
// 183.400 us; speedup vs baseline: 1.1451x; 1.1078x over previous
//
#include <hip/hip_runtime.h>
#include <stdint.h>

typedef __attribute__((ext_vector_type(8))) short bf16x8;
typedef __attribute__((ext_vector_type(4))) float f32x4;

__device__ __forceinline__ uint16_t f2bf(float f) {
  union { float f; uint32_t u; } a; a.f = f;
  uint32_t u = a.u;
  u += 0x7FFFu + ((u >> 16) & 1u);   // RTNE
  return (uint16_t)(u >> 16);
}

__device__ __forceinline__ uint32_t pk_bf16(float a, float b) {
#if __has_builtin(__builtin_amdgcn_cvt_pk_bf16_f32)
  auto r = __builtin_amdgcn_cvt_pk_bf16_f32(a, b);
  uint32_t u; __builtin_memcpy(&u, &r, sizeof(u));
  return u;
#else
  return (uint32_t)f2bf(a) | ((uint32_t)f2bf(b) << 16);
#endif
}

__device__ __forceinline__ uint32_t pk_bf16_fast(float a, float b) {
#if __has_builtin(__builtin_amdgcn_cvt_pk_bf16_f32)
  auto r = __builtin_amdgcn_cvt_pk_bf16_f32(a, b);
  uint32_t u; __builtin_memcpy(&u, &r, sizeof(u));
  return u;
#else
  uint32_t ua, ub;
  __builtin_memcpy(&ua, &a, 4); __builtin_memcpy(&ub, &b, 4);
  return __builtin_amdgcn_perm(ub, ua, 0x07060302u);
#endif
}

__device__ __forceinline__ float fast_exp2(float x) {
#if __has_builtin(__builtin_amdgcn_exp2f)
  return __builtin_amdgcn_exp2f(x);
#else
  return exp2f(x);
#endif
}

__device__ __forceinline__ void gld_lds16(const uint16_t* g, uint16_t* l) {
  __builtin_amdgcn_global_load_lds(
      (const __attribute__((address_space(1))) void*)g,
      (__attribute__((address_space(3))) void*)l, 16, 0, 0);
}

// ---------------- fused cast fp32 -> bf16 ----------------
__global__ void cast_all(const float* __restrict__ x, const float* __restrict__ wq,
                         const float* __restrict__ wk, const float* __restrict__ wv,
                         const float* __restrict__ wff,
                         uint16_t* __restrict__ xb, uint16_t* __restrict__ wqb,
                         uint16_t* __restrict__ wkb, uint16_t* __restrict__ wvb,
                         uint16_t* __restrict__ wffb) {
  int i = blockIdx.x * blockDim.x + threadIdx.x;
  const float* src; uint16_t* dst; int off;
  if (i < 1048576)      { src = x;   dst = xb;   off = i; }
  else if (i < 1310720) { src = wq;  dst = wqb;  off = i - 1048576; }
  else if (i < 1572864) { src = wk;  dst = wkb;  off = i - 1310720; }
  else if (i < 1835008) { src = wv;  dst = wvb;  off = i - 1572864; }
  else                  { src = wff; dst = wffb; off = i - 1835008; }
  float4 v = ((const float4*)src)[off];
  uint2 o; o.x = pk_bf16(v.x, v.y); o.y = pk_bf16(v.z, v.w);
  ((uint2*)dst)[off] = o;
}

// ---------------- shared GEMM mainloop (R5, proven) ----------------
__device__ __forceinline__ void gemm_tile(const uint16_t* __restrict__ Abase,
                                          const uint16_t* __restrict__ Bbase,
                                          uint16_t* lds, f32x4 acc[4][4]) {
  const int tid  = threadIdx.x;
  const int w    = tid >> 6;
  const int lane = tid & 63;
  const int wm   = w >> 1, wn = w & 1;
  const int lrow = lane & 15;
  const int quad = lane >> 4;
  const int srow = lane >> 3;
  const int lc   = (lane & 7) ^ srow;
  const int sx   = lrow & 7;
  uint16_t* a_lds = lds;
  uint16_t* b_lds = lds + 8192;

#pragma unroll
  for (int mt = 0; mt < 4; ++mt)
#pragma unroll
    for (int nt = 0; nt < 4; ++nt)
      acc[mt][nt] = (f32x4){0.f, 0.f, 0.f, 0.f};

  const uint16_t* ag = Abase + (size_t)(w * 32 + srow) * 1024 + lc * 8;
  const uint16_t* bg = Bbase + (size_t)(w * 32 + srow) * 1024 + lc * 8;

  for (int k0 = 0; k0 < 1024; k0 += 64) {
#pragma unroll
    for (int i8 = 0; i8 < 4; ++i8) {
      gld_lds16(ag + (size_t)i8 * 8 * 1024 + k0, a_lds + (w * 4 + i8) * 512);
      gld_lds16(bg + (size_t)i8 * 8 * 1024 + k0, b_lds + (w * 4 + i8) * 512);
    }
    __syncthreads();
#pragma unroll
    for (int ks = 0; ks < 2; ++ks) {
      bf16x8 af[4], bfr[4];
      const int c = ((ks * 4 + quad) ^ sx) << 3;
#pragma unroll
      for (int mt = 0; mt < 4; ++mt)
        af[mt] = *(const bf16x8*)(a_lds + (wm * 64 + mt * 16 + lrow) * 64 + c);
#pragma unroll
      for (int nt = 0; nt < 4; ++nt)
        bfr[nt] = *(const bf16x8*)(b_lds + (wn * 64 + nt * 16 + lrow) * 64 + c);
#pragma unroll
      for (int mt = 0; mt < 4; ++mt)
#pragma unroll
        for (int nt = 0; nt < 4; ++nt)
          acc[mt][nt] = __builtin_amdgcn_mfma_f32_16x16x32_bf16(af[mt], bfr[nt], acc[mt][nt], 0, 0, 0);
    }
    __syncthreads();
  }
}

// ---------------- QKV projection (R5, proven): 768 blocks ----------------
__global__ __launch_bounds__(256) void gemm_qkv(
    const uint16_t* __restrict__ x,
    const uint16_t* __restrict__ wq, const uint16_t* __restrict__ wk, const uint16_t* __restrict__ wv,
    uint16_t* __restrict__ qo, uint16_t* __restrict__ ko, uint16_t* __restrict__ vto) {
  __shared__ __align__(16) uint16_t lds[17408];
  const int m0 = blockIdx.x * 128, n0 = blockIdx.y * 128, z = blockIdx.z;
  f32x4 acc[4][4];
  if (z < 2) {
    const uint16_t* W = (z == 0) ? wq : wk;
    gemm_tile(W + (size_t)n0 * 1024, x + (size_t)m0 * 1024, lds, acc);
  } else {
    gemm_tile(x + (size_t)m0 * 1024, wv + (size_t)n0 * 1024, lds, acc);
  }

  const int tid = threadIdx.x;
  const int lane = tid & 63, w = tid >> 6;
  const int wm = w >> 1, wn = w & 1, lrow = lane & 15, quad = lane >> 4;
  const float scale = (z == 0) ? 0.045084222f : 1.0f;  // fold log2(e)/sqrt(1024) into Q

#pragma unroll
  for (int mt = 0; mt < 4; ++mt)
#pragma unroll
    for (int nt = 0; nt < 4; ++nt) {
      int i0 = wm * 64 + mt * 16 + quad * 4;
      int j  = wn * 64 + nt * 16 + lrow;
      uint2 dd;
      dd.x = pk_bf16(acc[mt][nt][0] * scale, acc[mt][nt][1] * scale);
      dd.y = pk_bf16(acc[mt][nt][2] * scale, acc[mt][nt][3] * scale);
      *(uint2*)(&lds[j * 136 + i0]) = dd;
    }
  __syncthreads();

  uint16_t* outp = (z == 0) ? qo : (z == 1) ? ko : vto;
  if (z < 2) {
#pragma unroll
    for (int it = 0; it < 8; ++it) {
      int idx = it * 256 + tid;
      int jj = idx >> 4, cc = idx & 15;
      uint4 v = *(const uint4*)(&lds[jj * 136 + cc * 8]);
      int m = m0 + jj, n = n0 + cc * 8;
      int b = m >> 11, s = m & 2047, h = n >> 6, dh = n & 63;
      *(uint4*)(outp + ((size_t)((b * 16 + h) * 2048 + s)) * 64 + dh) = v;
    }
  } else {
    int b = m0 >> 11, sbase = m0 & 2047;
#pragma unroll
    for (int it = 0; it < 8; ++it) {
      int idx = it * 256 + tid;
      int ff = idx >> 4, cc = idx & 15;
      uint4 v = *(const uint4*)(&lds[ff * 136 + cc * 8]);
      int n = n0 + ff, h = n >> 6, dh = n & 63;
      *(uint4*)(outp + ((size_t)((b * 16 + h) * 64 + dh)) * 2048 + sbase + cc * 8) = v;
    }
  }
}

// ---------------- FF (R5, proven) ----------------
__global__ __launch_bounds__(256) void gemm_ff(
    const uint16_t* __restrict__ ao, const uint16_t* __restrict__ wff,
    const float* __restrict__ bff, float* __restrict__ out) {
  __shared__ __align__(16) uint16_t lds[17408];
  const int m0 = blockIdx.x * 128, n0 = blockIdx.y * 128;
  f32x4 acc[4][4];
  gemm_tile(wff + (size_t)n0 * 1024, ao + (size_t)m0 * 1024, lds, acc);

  const int tid = threadIdx.x;
  const int lane = tid & 63, w = tid >> 6;
  const int wm = w >> 1, wn = w & 1, lrow = lane & 15, quad = lane >> 4;
  float* fl = (float*)lds;

#pragma unroll
  for (int p = 0; p < 2; ++p) {
    if (wm == p) {
#pragma unroll
      for (int mt = 0; mt < 4; ++mt)
#pragma unroll
        for (int nt = 0; nt < 4; ++nt) {
          int i0 = mt * 16 + quad * 4;
          int j  = wn * 64 + nt * 16 + lrow;
          *(f32x4*)(&fl[j * 68 + i0]) = acc[mt][nt];
        }
    }
    __syncthreads();
#pragma unroll
    for (int it = 0; it < 8; ++it) {
      int idx = it * 256 + tid;
      int jj = idx >> 4, cc = idx & 15;
      f32x4 v = *(const f32x4*)(&fl[jj * 68 + cc * 4]);
      int n = n0 + p * 64 + cc * 4;
      f32x4 bias = *(const f32x4*)(bff + n);
      f32x4 vv = v + bias;
      *(f32x4*)(out + (size_t)(m0 + jj) * 1024 + n) = vv;
    }
    __syncthreads();
  }
}

// ---------------- flash attention: wave-split S^T / PV, race-free (V in registers) ----------------
// Block = 128 qrows, 4 waves. S^T: wave w -> keys [16w,16w+16) x 128 qrows.
// PV lagged 1 iter; V fragments carried in REGISTERS across the iteration boundary
// (fixes R8 race: PV no longer reads the V LDS buffer that stage(kb+1) overwrites).
// PV: wave (pk,pq) -> O-partial over key-half pk for qrow-half pq.
__global__ __launch_bounds__(256, 2) void attn(
    const uint16_t* __restrict__ q, const uint16_t* __restrict__ k,
    const uint16_t* __restrict__ vt, uint16_t* __restrict__ ao) {
  __shared__ __align__(16) uint16_t k_lds[2][4096];   // [buf][key 64][dh 64], swizzled
  __shared__ __align__(16) uint16_t v_lds[2][4096];   // [buf][dh 64][key 64], swizzled
  __shared__ __align__(16) uint16_t p_lds[2][8192];   // [buf][qrow 128][key 64], swizzled
  const int tid = threadIdx.x, w = tid >> 6, lane = tid & 63;
  const int lrow = lane & 15, quad = lane >> 4;
  const int srow = lane >> 3, lc = (lane & 7) ^ srow, sx = lrow & 7;
  const int pk = w >> 1, pq = w & 1;
  const int pswz = (lrow & 3) << 2;
  const int bh = blockIdx.y, qb = blockIdx.x;
  const uint16_t* Q = q  + (size_t)bh * (2048 * 64);
  const uint16_t* K = k  + (size_t)bh * (2048 * 64);
  const uint16_t* V = vt + (size_t)bh * (64 * 2048);

  const int qr0 = qb * 128;
  bf16x8 qf[8][2];   // [qchunk 0..7][ks]: B-frag, n=qrow=qh*16+lrow, k=dh (scale pre-folded)
#pragma unroll
  for (int qh = 0; qh < 8; ++qh)
#pragma unroll
    for (int ks = 0; ks < 2; ++ks)
      qf[qh][ks] = *(const bf16x8*)(Q + (size_t)(qr0 + qh * 16 + lrow) * 64 + ks * 32 + quad * 8);

  f32x4 o[4][4];     // O-partial: [qh(half) 0..3][dt]; dh=dt*16+quad*4+r, qrow=pq*64+qh*16+lrow
#pragma unroll
  for (int qh = 0; qh < 4; ++qh)
#pragma unroll
    for (int dt = 0; dt < 4; ++dt) o[qh][dt] = (f32x4){0.f, 0.f, 0.f, 0.f};
  float ls[8] = {0.f, 0.f, 0.f, 0.f, 0.f, 0.f, 0.f, 0.f};
  bf16x8 vfr[4];     // V(kb) A-fragments, carried to iteration kb+1

  auto stage = [&](int kb, int bi) {
#pragma unroll
    for (int i2 = 0; i2 < 2; ++i2) {
      int i8 = w * 2 + i2;
      gld_lds16(K + (size_t)(kb * 64 + i8 * 8 + srow) * 64 + lc * 8, &k_lds[bi][i8 * 512]);
      gld_lds16(V + (size_t)(i8 * 8 + srow) * 2048 + kb * 64 + lc * 8, &v_lds[bi][i8 * 512]);
    }
  };
  stage(0, 0);

  for (int kb = 0; kb < 32; ++kb) {
    const int bi = kb & 1;
    __syncthreads();   // staging for kb drained; P(kb-1) visible; prev-iter LDS reads done

    if (kb > 0) {
      // PV(kb-1): O += V^T(kb-1) * P^T(kb-1); V from registers (race-free)
      const uint16_t* pbuf = p_lds[bi ^ 1];
#pragma unroll
      for (int qh = 0; qh < 4; ++qh) {
        int row = pq * 64 + qh * 16 + lrow;
        bf16x8 pa = *(const bf16x8*)(pbuf + row * 64 + (((pk * 8 + quad * 2) ^ pswz) << 2));
#pragma unroll
        for (int dt = 0; dt < 4; ++dt)
          o[qh][dt] = __builtin_amdgcn_mfma_f32_16x16x32_bf16(vfr[dt], pa, o[qh][dt], 0, 0, 0);
      }
    }

    // load V(kb) fragments from v_lds[bi] (stable: stage below writes bi^1 only)
#pragma unroll
    for (int dt = 0; dt < 4; ++dt)
      vfr[dt] = *(const bf16x8*)(&v_lds[bi][(dt * 16 + lrow) * 64 + (((pk * 4 + quad) ^ sx) << 3)]);

    if (kb + 1 < 32) stage(kb + 1, bi ^ 1);

    // S^T(kb): keys w*16..+16 x 128 qrows; s[qh]: key=w*16+quad*4+r, qrow=qh*16+lrow
    f32x4 s[8];
#pragma unroll
    for (int qh = 0; qh < 8; ++qh) s[qh] = (f32x4){0.f, 0.f, 0.f, 0.f};
#pragma unroll
    for (int ks = 0; ks < 2; ++ks) {
      bf16x8 kf = *(const bf16x8*)(&k_lds[bi][(w * 16 + lrow) * 64 + (((ks * 4 + quad) ^ sx) << 3)]);
#pragma unroll
      for (int qh = 0; qh < 8; ++qh)
        s[qh] = __builtin_amdgcn_mfma_f32_16x16x32_bf16(kf, qf[qh][ks], s[qh], 0, 0, 0);
    }

    // exp2 + l partials + P(kb) write to p_lds[bi]
    uint16_t* pbw = p_lds[bi];
#pragma unroll
    for (int qh = 0; qh < 8; ++qh) {
      float p0 = fast_exp2(s[qh][0]);
      float p1 = fast_exp2(s[qh][1]);
      float p2 = fast_exp2(s[qh][2]);
      float p3 = fast_exp2(s[qh][3]);
      ls[qh] += (p0 + p1) + (p2 + p3);
      uint2 dd; dd.x = pk_bf16_fast(p0, p1); dd.y = pk_bf16_fast(p2, p3);
      int row = qh * 16 + lrow;
      *(uint2*)(pbw + row * 64 + (((w * 4 + quad) ^ pswz) << 2)) = dd;
    }
  }

  // final PV(31): P in p_lds[1], V(31) in registers
  __syncthreads();
  {
    const uint16_t* pbuf = p_lds[1];
#pragma unroll
    for (int qh = 0; qh < 4; ++qh) {
      int row = pq * 64 + qh * 16 + lrow;
      bf16x8 pa = *(const bf16x8*)(pbuf + row * 64 + (((pk * 8 + quad * 2) ^ pswz) << 2));
#pragma unroll
      for (int dt = 0; dt < 4; ++dt)
        o[qh][dt] = __builtin_amdgcn_mfma_f32_16x16x32_bf16(vfr[dt], pa, o[qh][dt], 0, 0, 0);
    }
  }
  __syncthreads();   // final PV reads done before LDS is reused below

  // l: reduce over quads -> each lane holds this wave's 16-key sum for qrow qh*16+lrow
#pragma unroll
  for (int qh = 0; qh < 8; ++qh) {
    ls[qh] += __shfl_xor(ls[qh], 16);
    ls[qh] += __shfl_xor(ls[qh], 32);
  }
  float* lred  = (float*)&k_lds[0][0];   // [wave 4][qrow 128]
  float* arena = (float*)&p_lds[0][0];   // [qrow 128][dh 64] fp32 (32 KB)
  if (quad == 0) {
#pragma unroll
    for (int qh = 0; qh < 8; ++qh) lred[w * 128 + qh * 16 + lrow] = ls[qh];
  }
  if (pk == 1) {
#pragma unroll
    for (int qh = 0; qh < 4; ++qh)
#pragma unroll
      for (int dt = 0; dt < 4; ++dt)
        *(f32x4*)(&arena[(pq * 64 + qh * 16 + lrow) * 64 + dt * 16 + quad * 4]) = o[qh][dt];
  }
  __syncthreads();

  if (pk == 0) {
    const int b = bh >> 4, h = bh & 15;
#pragma unroll
    for (int qh = 0; qh < 4; ++qh) {
      int qrow = pq * 64 + qh * 16 + lrow;   // block-relative
      float l = lred[qrow] + lred[128 + qrow] + lred[256 + qrow] + lred[384 + qrow];
      float inv = 1.0f / l;
      int sg = qr0 + qrow;
#pragma unroll
      for (int dt = 0; dt < 4; ++dt) {
        f32x4 a = *(const f32x4*)(&arena[qrow * 64 + dt * 16 + quad * 4]);
        uint2 dd;
        dd.x = pk_bf16((o[qh][dt][0] + a[0]) * inv, (o[qh][dt][1] + a[1]) * inv);
        dd.y = pk_bf16((o[qh][dt][2] + a[2]) * inv, (o[qh][dt][3] + a[3]) * inv);
        *(uint2*)(ao + (size_t)(b * 2048 + sg) * 1024 + h * 64 + dt * 16 + quad * 4) = dd;
      }
    }
  }
}

extern "C" void kernel_launch(void* const* d_in, const int* in_sizes, int n_in,
                              void* d_out, int out_size, void* d_ws, size_t ws_size,
                              hipStream_t stream) {
  const float* x   = (const float*)d_in[0];
  const float* Wq  = (const float*)d_in[1];
  const float* Wk  = (const float*)d_in[2];
  const float* Wv  = (const float*)d_in[3];
  const float* Wff = (const float*)d_in[4];
  const float* bff = (const float*)d_in[5];
  float* out = (float*)d_out;

  uint16_t* ws = (uint16_t*)d_ws;
  uint16_t* x_bf   = ws;                 // 4M elems
  uint16_t* wq_bf  = ws + 4194304;       // 1M
  uint16_t* wk_bf  = ws + 5242880;       // 1M
  uint16_t* wv_bf  = ws + 6291456;       // 1M
  uint16_t* wff_bf = ws + 7340032;       // 1M
  uint16_t* q_bf   = ws + 8388608;       // 4M  (b,h,s,dh), pre-scaled by log2e/sqrt(D)
  uint16_t* k_bf   = ws + 12582912;      // 4M  (b,h,s,dh)
  uint16_t* vt_bf  = ws + 16777216;      // 4M  (b,h,dh,s)
  uint16_t* ao_bf  = ws + 20971520;      // 4M  (b,s,h*64+dh)

  cast_all<<<8192, 256, 0, stream>>>(x, Wq, Wk, Wv, Wff, x_bf, wq_bf, wk_bf, wv_bf, wff_bf);

  gemm_qkv<<<dim3(32, 8, 3), 256, 0, stream>>>(x_bf, wq_bf, wk_bf, wv_bf, q_bf, k_bf, vt_bf);
  attn<<<dim3(16, 32), 256, 0, stream>>>(q_bf, k_bf, vt_bf, ao_bf);
  gemm_ff<<<dim3(32, 8), 256, 0, stream>>>(ao_bf, wff_bf, bff, out);
}